// Round 7
// baseline (998.202 us; speedup 1.0000x reference)
//
#include <hip/hip_runtime.h>
#include <hip/hip_bf16.h>
#include <math.h>

// Problem constants (fixed by the reference)
#define TOK   131072L       // B * H * W = 8 * 128 * 128
#define LOG2E 1.4426950408889634f

typedef __hip_bfloat16  bf16;
typedef __hip_bfloat162 bf162;
typedef __attribute__((ext_vector_type(8))) short  bf16x8;   // MFMA A/B frag (4 VGPR)
typedef __attribute__((ext_vector_type(4))) float  f32x4;    // MFMA C/D frag

__device__ __forceinline__ float gelu_f(float v) {
    return 0.5f * v * (1.0f + erff(v * 0.70710678118654752f));
}
__device__ __forceinline__ short bf16bits(float v) {
    union { bf16 h; short s; } u; u.h = __float2bfloat16(v); return u.s;
}
__device__ __forceinline__ unsigned int cvtpk_bf16(float lo, float hi) {
    unsigned int r;
    asm("v_cvt_pk_bf16_f32 %0, %1, %2" : "=v"(r) : "v"(lo), "v"(hi));
    return r;
}

// ---------------- LayerNorm over rows of 180, fp32 in -> bf16 out -------------
__global__ __launch_bounds__(256) void ln_kernel(const float* __restrict__ x,
        const float* __restrict__ w, const float* __restrict__ b,
        bf16* __restrict__ out) {
    const int lane = threadIdx.x & 63;
    const long row = ((long)blockIdx.x << 2) + (threadIdx.x >> 6);
    const float* xr = x + row * 180;
    float v0 = xr[lane];
    float v1 = xr[lane + 64];
    float v2 = (lane < 52) ? xr[lane + 128] : 0.0f;
    float s  = v0 + v1 + v2;
    float sq = v0 * v0 + v1 * v1 + v2 * v2;
    #pragma unroll
    for (int off = 32; off > 0; off >>= 1) {
        s  += __shfl_xor(s, off);
        sq += __shfl_xor(sq, off);
    }
    const float mean = s * (1.0f / 180.0f);
    const float var  = sq * (1.0f / 180.0f) - mean * mean;
    const float rs   = rsqrtf(var + 1e-5f);
    bf16* orow = out + row * 180;
    orow[lane]      = __float2bfloat16((v0 - mean) * rs * w[lane]      + b[lane]);
    orow[lane + 64] = __float2bfloat16((v1 - mean) * rs * w[lane + 64] + b[lane + 64]);
    if (lane < 52)
        orow[lane + 128] = __float2bfloat16((v2 - mean) * rs * w[lane + 128] + b[lane + 128]);
}

// ------- W transpose+pad: fp32 [K][N] -> bf16 [NP][KP], zero-filled pads ------
template<int K, int N, int KP, int NP>
__global__ __launch_bounds__(256) void wtrans_kernel(const float* __restrict__ W,
        bf16* __restrict__ WT) {
    const int idx = blockIdx.x * 256 + threadIdx.x;
    if (idx >= KP * NP) return;
    const int n = idx / KP, k = idx - n * KP;
    WT[idx] = (n < N && k < K) ? __float2bfloat16(W[k * N + n])
                               : __float2bfloat16(0.0f);
}

// ---------------- zero a small guard strip (keeps K-overrun reads finite) -----
__global__ void guardz_kernel(bf16* __restrict__ g) {
    if (threadIdx.x < 192) g[threadIdx.x] = __float2bfloat16(0.0f);
}

// ---------------- X-stationary MFMA GEMM ---------------------------------------
// out[M,N] = A_bf16[M,AS(logical K)] @ W + bias (+epi).  W pre-transposed,
// K-padded to KP=NCH*192 and N-padded to NPAN*64, zero-filled -> staging is
// UNCONDITIONAL (X K-pad reads neighbor-row garbage, nullified by W zeros).
// X panel (64 rows) staged ONCE; loop over NPAN 64-col W panels (per-chunk
// restage for NCH=2).  Epilogue stores directly from accumulators.
// MODE 0: qkv (scale cols<180), bf16 out | 1: fc1 (GELU), bf16 out
// MODE 2: proj (+f32 resid), f32 out     | 3: fc2 (+f32 resid), f32 out
template<int AS, int NCH, int NPAN, int NCOLS, int MODE>
__global__ __launch_bounds__(256) void gemm_xstat(
        const bf16* __restrict__ A, const bf16* __restrict__ WT,
        const float* __restrict__ bias, const float* __restrict__ resid,
        void* __restrict__ outv) {
    constexpr int XSW = NCH * 200;          // xs row stride (shorts)
    constexpr int KP  = NCH * 192;
    __shared__ short xs [64 * XSW];         // X panel: xs[r][c*200 + k]
    __shared__ short wsm[64 * 200];         // W panel (one 192-chunk)
    const int tid  = threadIdx.x;
    const int wave = tid >> 6;
    const int lane = tid & 63;
    const int n15  = lane & 15;
    const int quad = lane >> 4;
    const long row0 = (long)blockIdx.x * 64;
    const int r   = tid >> 2;
    const int seg = (tid & 3) * 48;

    // ---- stage X once: unconditional 8B loads ----
    #pragma unroll
    for (int c = 0; c < NCH; ++c) {
        const bf16* arow = A + (row0 + r) * AS + c * 192 + seg;
        #pragma unroll
        for (int i = 0; i < 48; i += 4)
            *(short4*)(xs + r * XSW + c * 200 + seg + i) = *(const short4*)(arow + i);
    }

    for (int p = 0; p < NPAN; ++p) {
        f32x4 acc[4] = {};
        #pragma unroll
        for (int c = 0; c < NCH; ++c) {
            __syncthreads();   // prior MFMA reads of wsm done (also covers xs writes)
            {   // stage W panel p, chunk c: unconditional 16B loads
                const bf16* wrow = WT + (long)(p * 64 + r) * KP + c * 192 + seg;
                #pragma unroll
                for (int i = 0; i < 48; i += 8)
                    *(bf16x8*)(wsm + r * 200 + seg + i) = *(const bf16x8*)(wrow + i);
            }
            __syncthreads();
            #pragma unroll
            for (int s = 0; s < 6; ++s) {
                const int k0 = s * 32;
                const bf16x8 bfrag = *(const bf16x8*)(xs + (wave * 16 + n15) * XSW
                                                      + c * 200 + k0 + quad * 8);
                #pragma unroll
                for (int t = 0; t < 4; ++t) {
                    const bf16x8 afrag = *(const bf16x8*)(wsm + (t * 16 + n15) * 200
                                                          + k0 + quad * 8);
                    acc[t] = __builtin_amdgcn_mfma_f32_16x16x32_bf16(afrag, bfrag, acc[t], 0, 0, 0);
                }
            }
        }
        // ---- epilogue: lane owns row (wave*16+n15), cols p*64 + t*16 + quad*4 ----
        const long grow = row0 + wave * 16 + n15;
        #pragma unroll
        for (int t = 0; t < 4; ++t) {
            const int col4 = p * 64 + t * 16 + quad * 4;
            if (col4 >= NCOLS) continue;
            float v[4];
            #pragma unroll
            for (int j = 0; j < 4; ++j) v[j] = acc[t][j] + bias[col4 + j];
            if (MODE == 0) {
                if (col4 < 180) {
                    #pragma unroll
                    for (int j = 0; j < 4; ++j) v[j] *= 0.18257418583505536f;
                }
            } else if (MODE == 1) {
                #pragma unroll
                for (int j = 0; j < 4; ++j) v[j] = gelu_f(v[j]);
            } else {
                const float4 rv = *(const float4*)(resid + grow * NCOLS + col4);
                v[0] += rv.x; v[1] += rv.y; v[2] += rv.z; v[3] += rv.w;
            }
            if (MODE == 0 || MODE == 1) {
                short4 ou;
                ou.x = bf16bits(v[0]); ou.y = bf16bits(v[1]);
                ou.z = bf16bits(v[2]); ou.w = bf16bits(v[3]);
                *(short4*)((bf16*)outv + grow * NCOLS + col4) = ou;
            } else {
                *(f32x4*)((float*)outv + grow * NCOLS + col4) = *(f32x4*)v;
            }
        }
    }
}

// ---------------- relative-position bias table, [h][q][k] orientation ---------
__global__ __launch_bounds__(256) void biast_kernel(const float* __restrict__ rpb,
        const int* __restrict__ rpi, float* __restrict__ biasN) {
    const int idx = blockIdx.x * 256 + threadIdx.x;   // idx = q*256 + k
    const int r = rpi[idx];
    #pragma unroll
    for (int h = 0; h < 6; ++h)
        biasN[h * 65536 + idx] = rpb[r * 6 + h];
}

// ---------------- MFMA windowed attention: one block per (window, head) -------
// 4 waves x 64 queries, ONE barrier (post-staging).  Keys are staged into Ks
// PERMUTED (row s holds key with bit4 <-> bits3:2 swapped within each 32-block)
// so that QK^T's accumulator rows land exactly in the A-operand layout of the
// PV 16x16x32 MFMA: lane(q15,quad) of tiles kt=2kc,2kc+1 holds
// P[query=q15][key=kc*32+quad*8+j].  cvt_pk the accumulator -> registers ->
// PV directly; no P LDS round-trip, no per-qt barrier, no lsum (shfl instead).
#define SK 40    // Ks row stride (bf16): 2-way-free banks, 16B aligned
#define SP 264   // Vt row stride (bf16): 2-way-free banks, 16B aligned
__global__ __launch_bounds__(256, 4) void attn_mfma(
        const bf16* __restrict__ qkv, const float* __restrict__ biasN,
        bf16* __restrict__ attn_out) {
    __shared__ short Ks[256 * SK];       // 20480 B [perm-row][dim0..29,pad->0]
    __shared__ short Vt[32 * SP];        // 16896 B [dim][key]  (actual key order)
    __shared__ int   regid[256];         //  1024 B (actual key order)

    const int whid = blockIdx.x;
    const int win  = whid / 6;
    const int head = whid - win * 6;
    const int bimg = win >> 6;
    const int wi   = win & 63;
    const int whr  = wi >> 3, wwc = wi & 7;
    const int tid  = threadIdx.x;

    // ---- stage K (permuted rows, zero-padded dims 30,31) and V^T; region ids ----
    {
        const int t = tid;                      // actual key 0..255
        const int i = t >> 4, jj = t & 15;
        const int p  = whr * 16 + i;
        const int qq = wwc * 16 + jj;
        const long gr = (long)bimg * 16384 + ((p + 8) & 127) * 128 + ((qq + 8) & 127);
        const int rh = (p  < 112) ? 0 : ((p  < 120) ? 1 : 2);
        const int rw = (qq < 112) ? 0 : ((qq < 120) ? 1 : 2);
        regid[t] = rh * 3 + rw;
        const short2* base2 = (const short2*)(qkv + gr * 540 + head * 30);
        // permuted Ks row: swap bit4 (kt parity) with bits3:2 (quad) in each 32-block
        const int sp = (t & ~31) | ((t & 4) << 2) | ((t >> 1) & 12) | (t & 3);
        short* krow = Ks + sp * SK;
        #pragma unroll
        for (int pp = 0; pp < 15; ++pp) {
            *(short2*)(krow + 2 * pp) = base2[90 + pp];        // k row
            const short2 vv = base2[180 + pp];                 // v dims 2pp,2pp+1
            Vt[(2 * pp)     * SP + t] = vv.x;
            Vt[(2 * pp + 1) * SP + t] = vv.y;
        }
        *(short2*)(krow + 30) = make_short2(0, 0);             // zero pad dims 30,31
        Vt[30 * SP + t] = 0;                                   // keep pad rows finite
        Vt[31 * SP + t] = 0;
    }
    __syncthreads();   // the ONLY block-wide sync; waves free-run afterwards

    const int lane = tid & 63, wave = tid >> 6;
    const int q15 = lane & 15, quad = lane >> 4;
    const bool boundary = (whr == 7) || (wwc == 7);
    const float* mybias = biasN + head * 65536;

    for (int qt = 0; qt < 4; ++qt) {
        const int qbase = wave * 64 + qt * 16;
        // ---- Q fragment (B-operand): query qbase+q15, dims quad*8..+7 ----
        const int qi = qbase + q15;
        const int pq  = whr * 16 + (qi >> 4);
        const int qqq = wwc * 16 + (qi & 15);
        const long grq = (long)bimg * 16384 + ((pq + 8) & 127) * 128 + ((qqq + 8) & 127);
        union { bf16x8 v; short2 s[4]; } qf;
        const short2* qb = (const short2*)(qkv + grq * 540 + head * 30) + quad * 4;
        #pragma unroll
        for (int j = 0; j < 4; ++j) qf.s[j] = qb[j];

        // ---- S = K·Q^T : 16 key-tiles over permuted rows ----
        // lane(q15,quad) row quad*4+r of tile kt = actual key
        //   (kt>>1)*32 + quad*8 + (kt&1)*4 + r
        f32x4 acc[16];
        #pragma unroll
        for (int kt = 0; kt < 16; ++kt) acc[kt] = (f32x4){0.f, 0.f, 0.f, 0.f};
        #pragma unroll
        for (int kt = 0; kt < 16; ++kt) {
            const bf16x8 kfrag = *(const bf16x8*)(Ks + (kt * 16 + q15) * SK + quad * 8);
            acc[kt] = __builtin_amdgcn_mfma_f32_16x16x32_bf16(kfrag, qf.v, acc[kt], 0, 0, 0);
        }

        // ---- softmax over 256 keys (bias/mask at PERMUTED key offsets) ----
        const int rtq = ((pq  < 112) ? 0 : ((pq  < 120) ? 1 : 2)) * 3
                      + ((qqq < 112) ? 0 : ((qqq < 120) ? 1 : 2));
        float mx = -1e30f;
        #pragma unroll
        for (int kt = 0; kt < 16; ++kt) {
            const int koff = (kt >> 1) * 32 + (quad << 3) + ((kt & 1) << 2);
            const float4 b4 = *(const float4*)(mybias + qi * 256 + koff);
            float bb[4] = {b4.x, b4.y, b4.z, b4.w};
            if (boundary) {
                const int4 rj = *(const int4*)(regid + koff);
                bb[0] += (rtq == rj.x) ? 0.f : -100.f;
                bb[1] += (rtq == rj.y) ? 0.f : -100.f;
                bb[2] += (rtq == rj.z) ? 0.f : -100.f;
                bb[3] += (rtq == rj.w) ? 0.f : -100.f;
            }
            #pragma unroll
            for (int r = 0; r < 4; ++r) {
                acc[kt][r] += bb[r];
                mx = fmaxf(mx, acc[kt][r]);
            }
        }
        mx = fmaxf(mx, __shfl_xor(mx, 16));
        mx = fmaxf(mx, __shfl_xor(mx, 32));
        float l = 0.f;
        unsigned int pk[32];   // pk[2kt],pk[2kt+1]: bf16 pairs, key-ascending
        #pragma unroll
        for (int kt = 0; kt < 16; ++kt) {
            float pv0 = __builtin_amdgcn_exp2f((acc[kt][0] - mx) * LOG2E);
            float pv1 = __builtin_amdgcn_exp2f((acc[kt][1] - mx) * LOG2E);
            float pv2 = __builtin_amdgcn_exp2f((acc[kt][2] - mx) * LOG2E);
            float pv3 = __builtin_amdgcn_exp2f((acc[kt][3] - mx) * LOG2E);
            l += pv0 + pv1 + pv2 + pv3;
            pk[2 * kt]     = cvtpk_bf16(pv0, pv1);
            pk[2 * kt + 1] = cvtpk_bf16(pv2, pv3);
        }
        l += __shfl_xor(l, 16);
        l += __shfl_xor(l, 32);   // all lanes (q15,*) now hold sum for query q15

        // ---- O = P·V : A-frag straight from registers (keys kc*32+quad*8+j) ----
        f32x4 o0 = (f32x4){0.f, 0.f, 0.f, 0.f};
        f32x4 o1 = (f32x4){0.f, 0.f, 0.f, 0.f};
        #pragma unroll
        for (int kc = 0; kc < 8; ++kc) {
            union { unsigned int w[4]; bf16x8 v; } pa;
            pa.w[0] = pk[4 * kc];     pa.w[1] = pk[4 * kc + 1];
            pa.w[2] = pk[4 * kc + 2]; pa.w[3] = pk[4 * kc + 3];
            const bf16x8 v0f = *(const bf16x8*)(Vt + q15 * SP + kc * 32 + quad * 8);
            const bf16x8 v1f = *(const bf16x8*)(Vt + (q15 + 16) * SP + kc * 32 + quad * 8);
            o0 = __builtin_amdgcn_mfma_f32_16x16x32_bf16(pa.v, v0f, o0, 0, 0, 0);
            o1 = __builtin_amdgcn_mfma_f32_16x16x32_bf16(pa.v, v1f, o1, 0, 0, 0);
        }
        // ---- normalize + scatter: lane holds O[query=quad*4+r][dim=q15,(+16)] ----
        #pragma unroll
        for (int r = 0; r < 4; ++r) {
            const int qr = qbase + quad * 4 + r;
            const float inv = 1.0f / __shfl(l, quad * 4 + r);   // sum of query quad*4+r
            const int pr  = whr * 16 + (qr >> 4);
            const int qqr = wwc * 16 + (qr & 15);
            const long gro = (long)bimg * 16384 + ((pr + 8) & 127) * 128 + ((qqr + 8) & 127);
            bf16* ob = attn_out + gro * 180 + head * 30;
            ob[q15] = __float2bfloat16(o0[r] * inv);
            if (q15 < 14) ob[q15 + 16] = __float2bfloat16(o1[r] * inv);
        }
    }
}

// ---------------- depthwise 5x5 conv + GELU + residual (z = y + gelu(conv)) ---
// Row-streaming with 1-step-ahead prefetch; six row buffers rotate statically.
__global__ __launch_bounds__(256) void dwconv_kernel(const bf16* __restrict__ y,
        const float* __restrict__ dww, const float* __restrict__ dwb,
        bf16* __restrict__ z) {
    __shared__ float wl[25 * 360];   // [tap][ch]
    __shared__ float bl[360];
    const int tid = threadIdx.x;
    for (int e = tid; e < 9000; e += 256) {
        const int ch = e / 25;
        const int tap = e - ch * 25;
        wl[tap * 360 + ch] = dww[e];
    }
    for (int e = tid; e < 360; e += 256) bl[e] = dwb[e];
    __syncthreads();

    const int gid = blockIdx.x * 256 + tid;
    const int g0  = gid / 180;
    const int pr  = gid - g0 * 180;
    const int xg  = g0 & 31;
    const int u   = g0 >> 5;
    const int im  = u >> 4;
    const int ph0 = (u & 15) << 3;         // band start row (8 rows per band)
    const int x0  = xg << 2;
    const float2 bias2 = *(const float2*)(bl + 2 * pr);

    const bf162* ybase = (const bf162*)y + ((long)im << 14) * 180 + pr;
    bf162*       zbase = (bf162*)z + (((long)im << 14) + ((long)ph0 << 7) + x0) * 180 + pr;

#define LOADROW(R, HY) { \
    const int hy_ = (HY); \
    if ((unsigned)hy_ < 128u) { \
        const bf162* row_ = ybase + ((long)hy_ << 7) * 180; \
        _Pragma("unroll") \
        for (int xx = 0; xx < 8; ++xx) { \
            const int wx_ = x0 + xx - 2; \
            R[xx] = ((unsigned)wx_ < 128u) ? __bfloat1622float2(row_[wx_ * 180]) \
                                           : make_float2(0.f, 0.f); \
        } \
    } else { \
        _Pragma("unroll") for (int xx = 0; xx < 8; ++xx) R[xx] = make_float2(0.f, 0.f); \
    } }

#define ACCJ(R, J) { \
    _Pragma("unroll") \
    for (int d = 0; d < 5; ++d) { \
        const float2 w2 = *(const float2*)(wl + ((J) * 5 + d) * 360 + 2 * pr); \
        s0.x += R[d].x     * w2.x; s0.y += R[d].y     * w2.y; \
        s1.x += R[d + 1].x * w2.x; s1.y += R[d + 1].y * w2.y; \
        s2.x += R[d + 2].x * w2.x; s2.y += R[d + 2].y * w2.y; \
        s3.x += R[d + 3].x * w2.x; s3.y += R[d + 3].y * w2.y; \
    } }

#define STEP(T, RA, RB, RC, RD, RE, RP, PF) { \
    if (PF) LOADROW(RP, ph0 + (T) + 3); \
    float2 s0 = bias2, s1 = bias2, s2 = bias2, s3 = bias2; \
    ACCJ(RA, 0); ACCJ(RB, 1); ACCJ(RC, 2); ACCJ(RD, 3); ACCJ(RE, 4); \
    bf162* zr = zbase + ((long)(T) << 7) * 180; \
    bf162 ov; \
    ov.x = __float2bfloat16(RC[2].x + gelu_f(s0.x)); \
    ov.y = __float2bfloat16(RC[2].y + gelu_f(s0.y)); zr[0]   = ov; \
    ov.x = __float2bfloat16(RC[3].x + gelu_f(s1.x)); \
    ov.y = __float2bfloat16(RC[3].y + gelu_f(s1.y)); zr[180] = ov; \
    ov.x = __float2bfloat16(RC[4].x + gelu_f(s2.x)); \
    ov.y = __float2bfloat16(RC[4].y + gelu_f(s2.y)); zr[360] = ov; \
    ov.x = __float2bfloat16(RC[5].x + gelu_f(s3.x)); \
    ov.y = __float2bfloat16(RC[5].y + gelu_f(s3.y)); zr[540] = ov; \
    }

    float2 r0[8], r1[8], r2[8], r3[8], r4[8], r5[8];
    LOADROW(r0, ph0 - 2);
    LOADROW(r1, ph0 - 1);
    LOADROW(r2, ph0);
    LOADROW(r3, ph0 + 1);
    LOADROW(r4, ph0 + 2);

    STEP(0, r0, r1, r2, r3, r4, r5, 1);
    STEP(1, r1, r2, r3, r4, r5, r0, 1);
    STEP(2, r2, r3, r4, r5, r0, r1, 1);
    STEP(3, r3, r4, r5, r0, r1, r2, 1);
    STEP(4, r4, r5, r0, r1, r2, r3, 1);
    STEP(5, r5, r0, r1, r2, r3, r4, 1);
    STEP(6, r0, r1, r2, r3, r4, r5, 1);
    STEP(7, r1, r2, r3, r4, r5, r0, 0);

#undef STEP
#undef ACCJ
#undef LOADROW
}

// ---------------- launch --------------------------------------------------------
extern "C" void kernel_launch(void* const* d_in, const int* in_sizes, int n_in,
                              void* d_out, int out_size, void* d_ws, size_t ws_size,
                              hipStream_t stream) {
    const float* x    = (const float*)d_in[0];
    // d_in[1] = attn_mask: unused (mask recomputed analytically in-kernel)
    const int*   rpi  = (const int*)d_in[2];
    const float* n1w  = (const float*)d_in[3];
    const float* n1b  = (const float*)d_in[4];
    const float* wqkv = (const float*)d_in[5];
    const float* bqkv = (const float*)d_in[6];
    const float* rpb  = (const float*)d_in[7];
    const float* pw   = (const float*)d_in[8];
    const float* pb   = (const float*)d_in[9];
    const float* n2w  = (const float*)d_in[10];
    const float* n2b  = (const float*)d_in[11];
    const float* f1w  = (const float*)d_in[12];
    const float* f1b  = (const float*)d_in[13];
    const float* dww  = (const float*)d_in[14];
    const float* dwb  = (const float*)d_in[15];
    const float* f2w  = (const float*)d_in[16];
    const float* f2b  = (const float*)d_in[17];
    float* out = (float*)d_out;

    // workspace: qkvb 141.6MB | abuf 47.2MB | guard | biasN 1.57MB | WT 0.59MB
    const size_t NEED = 540L * TOK * 2 + 180L * TOK * 2 + 192L * 2
                      + 393216L * 4 + 294912L * 2;
    if (ws_size < NEED) return;

    bf16* qkvb = (bf16*)d_ws;
    bf16* abuf = qkvb + 540L * TOK;
    bf16* ybuf = qkvb;                    // alias: qkv dead after attention
    bf16* zbuf = qkvb + 360L * TOK;       // spans qkvb tail + (abuf-adjacent)
    bf16* guard = qkvb + 720L * TOK;      // 192 zero shorts after abuf
    float* biasN = (float*)(guard + 192);
    bf16* wqkvT = (bf16*)(biasN + 393216);   // [576][192]
    bf16* projT = wqkvT + 110592;            // [192][192]
    bf16* fc1T  = projT + 36864;             // [384][192]
    bf16* fc2T  = fc1T + 73728;              // [192][384]

    wtrans_kernel<180, 540, 192, 576><<<432, 256, 0, stream>>>(wqkv, wqkvT);
    wtrans_kernel<180, 180, 192, 192><<<144, 256, 0, stream>>>(pw, projT);
    wtrans_kernel<180, 360, 192, 384><<<288, 256, 0, stream>>>(f1w, fc1T);
    wtrans_kernel<360, 180, 384, 192><<<288, 256, 0, stream>>>(f2w, fc2T);
    biast_kernel<<<256, 256, 0, stream>>>(rpb, rpi, biasN);
    guardz_kernel<<<1, 192, 0, stream>>>(guard);

    ln_kernel<<<32768, 256, 0, stream>>>(x, n1w, n1b, abuf);
    gemm_xstat<180, 1, 9, 540, 0><<<2048, 256, 0, stream>>>(abuf, wqkvT, bqkv, nullptr, qkvb);
    attn_mfma<<<3072, 256, 0, stream>>>(qkvb, biasN, abuf);         // abuf := attn_out
    gemm_xstat<180, 1, 3, 180, 2><<<2048, 256, 0, stream>>>(abuf, projT, pb, x, out);  // out := x2
    ln_kernel<<<32768, 256, 0, stream>>>(out, n2w, n2b, abuf);      // abuf := xn2
    gemm_xstat<180, 1, 6, 360, 1><<<2048, 256, 0, stream>>>(abuf, fc1T, f1b, nullptr, ybuf);
    dwconv_kernel<<<2880, 256, 0, stream>>>(ybuf, dww, dwb, zbuf);
    gemm_xstat<360, 2, 3, 180, 3><<<2048, 256, 0, stream>>>(zbuf, fc2T, f2b, out, out);
}

// Round 8
// 836.194 us; speedup vs baseline: 1.1937x; 1.1937x over previous
//
#include <hip/hip_runtime.h>
#include <hip/hip_bf16.h>
#include <math.h>

// Problem constants (fixed by the reference)
#define TOK   131072L       // B * H * W = 8 * 128 * 128
#define LOG2E 1.4426950408889634f

typedef __hip_bfloat16  bf16;
typedef __hip_bfloat162 bf162;
typedef __attribute__((ext_vector_type(8))) short  bf16x8;   // MFMA A/B frag (4 VGPR)
typedef __attribute__((ext_vector_type(4))) float  f32x4;    // MFMA C/D frag

__device__ __forceinline__ float gelu_f(float v) {
    return 0.5f * v * (1.0f + erff(v * 0.70710678118654752f));
}
__device__ __forceinline__ short bf16bits(float v) {
    union { bf16 h; short s; } u; u.h = __float2bfloat16(v); return u.s;
}
__device__ __forceinline__ unsigned int cvtpk_bf16(float lo, float hi) {
    unsigned int r;
    asm("v_cvt_pk_bf16_f32 %0, %1, %2" : "=v"(r) : "v"(lo), "v"(hi));
    return r;
}

// ---------------- LayerNorm over rows of 180, fp32 in -> bf16 out -------------
__global__ __launch_bounds__(256) void ln_kernel(const float* __restrict__ x,
        const float* __restrict__ w, const float* __restrict__ b,
        bf16* __restrict__ out) {
    const int lane = threadIdx.x & 63;
    const long row = ((long)blockIdx.x << 2) + (threadIdx.x >> 6);
    const float* xr = x + row * 180;
    float v0 = xr[lane];
    float v1 = xr[lane + 64];
    float v2 = (lane < 52) ? xr[lane + 128] : 0.0f;
    float s  = v0 + v1 + v2;
    float sq = v0 * v0 + v1 * v1 + v2 * v2;
    #pragma unroll
    for (int off = 32; off > 0; off >>= 1) {
        s  += __shfl_xor(s, off);
        sq += __shfl_xor(sq, off);
    }
    const float mean = s * (1.0f / 180.0f);
    const float var  = sq * (1.0f / 180.0f) - mean * mean;
    const float rs   = rsqrtf(var + 1e-5f);
    bf16* orow = out + row * 180;
    orow[lane]      = __float2bfloat16((v0 - mean) * rs * w[lane]      + b[lane]);
    orow[lane + 64] = __float2bfloat16((v1 - mean) * rs * w[lane + 64] + b[lane + 64]);
    if (lane < 52)
        orow[lane + 128] = __float2bfloat16((v2 - mean) * rs * w[lane + 128] + b[lane + 128]);
}

// ------- W transpose+pad: fp32 [K][N] -> bf16 [NP][KP], zero-filled pads ------
template<int K, int N, int KP, int NP>
__global__ __launch_bounds__(256) void wtrans_kernel(const float* __restrict__ W,
        bf16* __restrict__ WT) {
    const int idx = blockIdx.x * 256 + threadIdx.x;
    if (idx >= KP * NP) return;
    const int n = idx / KP, k = idx - n * KP;
    WT[idx] = (n < N && k < K) ? __float2bfloat16(W[k * N + n])
                               : __float2bfloat16(0.0f);
}

// ---------------- zero a small guard strip (keeps K-overrun reads finite) -----
__global__ void guardz_kernel(bf16* __restrict__ g) {
    if (threadIdx.x < 192) g[threadIdx.x] = __float2bfloat16(0.0f);
}

// ---------------- X-stationary MFMA GEMM ---------------------------------------
// out[M,N] = A_bf16[M,AS(logical K)] @ W + bias (+epi).  W pre-transposed,
// K-padded to KP=NCH*192 and N-padded to NPAN*64, zero-filled -> staging is
// UNCONDITIONAL (X K-pad reads neighbor-row garbage, nullified by W zeros).
// X panel (64 rows) staged ONCE; loop over NPAN 64-col W panels (per-chunk
// restage for NCH=2).  Epilogue stores directly from accumulators.
// MODE 0: qkv (scale cols<180), bf16 out | 1: fc1 (GELU), bf16 out
// MODE 2: proj (+f32 resid), f32 out     | 3: fc2 (+f32 resid), f32 out
template<int AS, int NCH, int NPAN, int NCOLS, int MODE>
__global__ __launch_bounds__(256) void gemm_xstat(
        const bf16* __restrict__ A, const bf16* __restrict__ WT,
        const float* __restrict__ bias, const float* __restrict__ resid,
        void* __restrict__ outv) {
    constexpr int XSW = NCH * 200;          // xs row stride (shorts)
    constexpr int KP  = NCH * 192;
    __shared__ short xs [64 * XSW];         // X panel: xs[r][c*200 + k]
    __shared__ short wsm[64 * 200];         // W panel (one 192-chunk)
    const int tid  = threadIdx.x;
    const int wave = tid >> 6;
    const int lane = tid & 63;
    const int n15  = lane & 15;
    const int quad = lane >> 4;
    const long row0 = (long)blockIdx.x * 64;
    const int r   = tid >> 2;
    const int seg = (tid & 3) * 48;

    // ---- stage X once: unconditional 8B loads ----
    #pragma unroll
    for (int c = 0; c < NCH; ++c) {
        const bf16* arow = A + (row0 + r) * AS + c * 192 + seg;
        #pragma unroll
        for (int i = 0; i < 48; i += 4)
            *(short4*)(xs + r * XSW + c * 200 + seg + i) = *(const short4*)(arow + i);
    }

    for (int p = 0; p < NPAN; ++p) {
        f32x4 acc[4] = {};
        #pragma unroll
        for (int c = 0; c < NCH; ++c) {
            __syncthreads();   // prior MFMA reads of wsm done (also covers xs writes)
            {   // stage W panel p, chunk c: unconditional 16B loads
                const bf16* wrow = WT + (long)(p * 64 + r) * KP + c * 192 + seg;
                #pragma unroll
                for (int i = 0; i < 48; i += 8)
                    *(bf16x8*)(wsm + r * 200 + seg + i) = *(const bf16x8*)(wrow + i);
            }
            __syncthreads();
            #pragma unroll
            for (int s = 0; s < 6; ++s) {
                const int k0 = s * 32;
                const bf16x8 bfrag = *(const bf16x8*)(xs + (wave * 16 + n15) * XSW
                                                      + c * 200 + k0 + quad * 8);
                #pragma unroll
                for (int t = 0; t < 4; ++t) {
                    const bf16x8 afrag = *(const bf16x8*)(wsm + (t * 16 + n15) * 200
                                                          + k0 + quad * 8);
                    acc[t] = __builtin_amdgcn_mfma_f32_16x16x32_bf16(afrag, bfrag, acc[t], 0, 0, 0);
                }
            }
        }
        // ---- epilogue: lane owns row (wave*16+n15), cols p*64 + t*16 + quad*4 ----
        const long grow = row0 + wave * 16 + n15;
        #pragma unroll
        for (int t = 0; t < 4; ++t) {
            const int col4 = p * 64 + t * 16 + quad * 4;
            if (col4 >= NCOLS) continue;
            float v[4];
            #pragma unroll
            for (int j = 0; j < 4; ++j) v[j] = acc[t][j] + bias[col4 + j];
            if (MODE == 0) {
                if (col4 < 180) {
                    #pragma unroll
                    for (int j = 0; j < 4; ++j) v[j] *= 0.18257418583505536f;
                }
            } else if (MODE == 1) {
                #pragma unroll
                for (int j = 0; j < 4; ++j) v[j] = gelu_f(v[j]);
            } else {
                const float4 rv = *(const float4*)(resid + grow * NCOLS + col4);
                v[0] += rv.x; v[1] += rv.y; v[2] += rv.z; v[3] += rv.w;
            }
            if (MODE == 0 || MODE == 1) {
                short4 ou;
                ou.x = bf16bits(v[0]); ou.y = bf16bits(v[1]);
                ou.z = bf16bits(v[2]); ou.w = bf16bits(v[3]);
                *(short4*)((bf16*)outv + grow * NCOLS + col4) = ou;
            } else {
                *(f32x4*)((float*)outv + grow * NCOLS + col4) = *(f32x4*)v;
            }
        }
    }
}

// ---------------- relative-position bias table, [h][q][k] orientation ---------
__global__ __launch_bounds__(256) void biast_kernel(const float* __restrict__ rpb,
        const int* __restrict__ rpi, float* __restrict__ biasN) {
    const int idx = blockIdx.x * 256 + threadIdx.x;   // idx = q*256 + k
    const int r = rpi[idx];
    #pragma unroll
    for (int h = 0; h < 6; ++h)
        biasN[h * 65536 + idx] = rpb[r * 6 + h];
}

// ---------------- MFMA windowed attention: one block per (window, head) -------
// 4 waves x 64 queries, ONE barrier (post-staging).  Keys staged into Ks
// PERMUTED (bit4 <-> bits3:2 within each 32-block) so QK^T's accumulator rows
// land exactly in the A-operand layout of the PV 16x16x32 MFMA.  The exp ->
// cvt_pk -> PV chain is FUSED per 32-key chunk so the packed-P array never
// materializes (register live-set ~90, no spill; R6's pk[32] spilled).
#define SK 40    // Ks row stride (bf16): 2-way-free banks, 16B aligned
#define SP 264   // Vt row stride (bf16): 2-way-free banks, 16B aligned
__global__ __launch_bounds__(256) void attn_mfma(
        const bf16* __restrict__ qkv, const float* __restrict__ biasN,
        bf16* __restrict__ attn_out) {
    __shared__ short Ks[256 * SK];       // 20480 B [perm-row][dim0..29,pad->0]
    __shared__ short Vt[32 * SP];        // 16896 B [dim][key]  (actual key order)
    __shared__ int   regid[256];         //  1024 B (actual key order)

    const int whid = blockIdx.x;
    const int win  = whid / 6;
    const int head = whid - win * 6;
    const int bimg = win >> 6;
    const int wi   = win & 63;
    const int whr  = wi >> 3, wwc = wi & 7;
    const int tid  = threadIdx.x;

    // ---- stage K (permuted rows, zero-padded dims 30,31) and V^T; region ids ----
    {
        const int t = tid;                      // actual key 0..255
        const int i = t >> 4, jj = t & 15;
        const int p  = whr * 16 + i;
        const int qq = wwc * 16 + jj;
        const long gr = (long)bimg * 16384 + ((p + 8) & 127) * 128 + ((qq + 8) & 127);
        const int rh = (p  < 112) ? 0 : ((p  < 120) ? 1 : 2);
        const int rw = (qq < 112) ? 0 : ((qq < 120) ? 1 : 2);
        regid[t] = rh * 3 + rw;
        const short2* base2 = (const short2*)(qkv + gr * 540 + head * 30);
        // permuted Ks row: swap bit4 (kt parity) with bits3:2 (quad) in each 32-block
        const int sp = (t & ~31) | ((t & 4) << 2) | ((t >> 1) & 12) | (t & 3);
        short* krow = Ks + sp * SK;
        #pragma unroll
        for (int pp = 0; pp < 15; ++pp) {
            *(short2*)(krow + 2 * pp) = base2[90 + pp];        // k row
            const short2 vv = base2[180 + pp];                 // v dims 2pp,2pp+1
            Vt[(2 * pp)     * SP + t] = vv.x;
            Vt[(2 * pp + 1) * SP + t] = vv.y;
        }
        *(short2*)(krow + 30) = make_short2(0, 0);             // zero pad dims 30,31
        Vt[30 * SP + t] = 0;                                   // keep pad rows finite
        Vt[31 * SP + t] = 0;
    }
    __syncthreads();   // the ONLY block-wide sync; waves free-run afterwards

    const int lane = tid & 63, wave = tid >> 6;
    const int q15 = lane & 15, quad = lane >> 4;
    const bool boundary = (whr == 7) || (wwc == 7);
    const float* mybias = biasN + head * 65536;

    for (int qt = 0; qt < 4; ++qt) {
        const int qbase = wave * 64 + qt * 16;
        // ---- Q fragment (B-operand): query qbase+q15, dims quad*8..+7 ----
        const int qi = qbase + q15;
        const int pq  = whr * 16 + (qi >> 4);
        const int qqq = wwc * 16 + (qi & 15);
        const long grq = (long)bimg * 16384 + ((pq + 8) & 127) * 128 + ((qqq + 8) & 127);
        union { bf16x8 v; short2 s[4]; } qf;
        const short2* qb = (const short2*)(qkv + grq * 540 + head * 30) + quad * 4;
        #pragma unroll
        for (int j = 0; j < 4; ++j) qf.s[j] = qb[j];

        // ---- S = K·Q^T : 16 key-tiles over permuted rows ----
        // lane(q15,quad) row quad*4+r of tile kt = actual key
        //   (kt>>1)*32 + quad*8 + (kt&1)*4 + r
        f32x4 acc[16];
        #pragma unroll
        for (int kt = 0; kt < 16; ++kt) acc[kt] = (f32x4){0.f, 0.f, 0.f, 0.f};
        #pragma unroll
        for (int kt = 0; kt < 16; ++kt) {
            const bf16x8 kfrag = *(const bf16x8*)(Ks + (kt * 16 + q15) * SK + quad * 8);
            acc[kt] = __builtin_amdgcn_mfma_f32_16x16x32_bf16(kfrag, qf.v, acc[kt], 0, 0, 0);
        }

        // ---- pass 1: bias+mask into acc, running max ----
        const int rtq = ((pq  < 112) ? 0 : ((pq  < 120) ? 1 : 2)) * 3
                      + ((qqq < 112) ? 0 : ((qqq < 120) ? 1 : 2));
        float mx = -1e30f;
        #pragma unroll
        for (int kt = 0; kt < 16; ++kt) {
            const int koff = (kt >> 1) * 32 + (quad << 3) + ((kt & 1) << 2);
            const float4 b4 = *(const float4*)(mybias + qi * 256 + koff);
            float bb[4] = {b4.x, b4.y, b4.z, b4.w};
            if (boundary) {
                const int4 rj = *(const int4*)(regid + koff);
                bb[0] += (rtq == rj.x) ? 0.f : -100.f;
                bb[1] += (rtq == rj.y) ? 0.f : -100.f;
                bb[2] += (rtq == rj.z) ? 0.f : -100.f;
                bb[3] += (rtq == rj.w) ? 0.f : -100.f;
            }
            #pragma unroll
            for (int r = 0; r < 4; ++r) {
                acc[kt][r] += bb[r];
                mx = fmaxf(mx, acc[kt][r]);
            }
        }
        mx = fmaxf(mx, __shfl_xor(mx, 16));
        mx = fmaxf(mx, __shfl_xor(mx, 32));

        // ---- pass 2 (FUSED): per 32-key chunk exp -> cvt_pk -> 2 PV MFMAs ----
        f32x4 o0 = (f32x4){0.f, 0.f, 0.f, 0.f};
        f32x4 o1 = (f32x4){0.f, 0.f, 0.f, 0.f};
        float l = 0.f;
        #pragma unroll
        for (int kc = 0; kc < 8; ++kc) {
            const float e0 = __builtin_amdgcn_exp2f((acc[2 * kc][0] - mx) * LOG2E);
            const float e1 = __builtin_amdgcn_exp2f((acc[2 * kc][1] - mx) * LOG2E);
            const float e2 = __builtin_amdgcn_exp2f((acc[2 * kc][2] - mx) * LOG2E);
            const float e3 = __builtin_amdgcn_exp2f((acc[2 * kc][3] - mx) * LOG2E);
            const float f0 = __builtin_amdgcn_exp2f((acc[2 * kc + 1][0] - mx) * LOG2E);
            const float f1 = __builtin_amdgcn_exp2f((acc[2 * kc + 1][1] - mx) * LOG2E);
            const float f2 = __builtin_amdgcn_exp2f((acc[2 * kc + 1][2] - mx) * LOG2E);
            const float f3 = __builtin_amdgcn_exp2f((acc[2 * kc + 1][3] - mx) * LOG2E);
            l += (e0 + e1 + e2 + e3) + (f0 + f1 + f2 + f3);
            union { unsigned int w[4]; bf16x8 v; } pa;
            pa.w[0] = cvtpk_bf16(e0, e1);
            pa.w[1] = cvtpk_bf16(e2, e3);
            pa.w[2] = cvtpk_bf16(f0, f1);
            pa.w[3] = cvtpk_bf16(f2, f3);
            const bf16x8 v0f = *(const bf16x8*)(Vt + q15 * SP + kc * 32 + quad * 8);
            const bf16x8 v1f = *(const bf16x8*)(Vt + (q15 + 16) * SP + kc * 32 + quad * 8);
            o0 = __builtin_amdgcn_mfma_f32_16x16x32_bf16(pa.v, v0f, o0, 0, 0, 0);
            o1 = __builtin_amdgcn_mfma_f32_16x16x32_bf16(pa.v, v1f, o1, 0, 0, 0);
        }
        l += __shfl_xor(l, 16);
        l += __shfl_xor(l, 32);   // l now depends only on q15 (query)

        // ---- normalize + scatter: lane holds O[query=quad*4+r][dim=q15,(+16)] ----
        #pragma unroll
        for (int r = 0; r < 4; ++r) {
            const int qr = qbase + quad * 4 + r;
            const float inv = 1.0f / __shfl(l, quad * 4 + r);   // sum of query quad*4+r
            const int pr  = whr * 16 + (qr >> 4);
            const int qqr = wwc * 16 + (qr & 15);
            const long gro = (long)bimg * 16384 + ((pr + 8) & 127) * 128 + ((qqr + 8) & 127);
            bf16* ob = attn_out + gro * 180 + head * 30;
            ob[q15] = __float2bfloat16(o0[r] * inv);
            if (q15 < 14) ob[q15 + 16] = __float2bfloat16(o1[r] * inv);
        }
    }
}

// ---------------- depthwise 5x5 conv + GELU + residual (z = y + gelu(conv)) ---
// Row-streaming with 1-step-ahead prefetch; six row buffers rotate statically.
__global__ __launch_bounds__(256) void dwconv_kernel(const bf16* __restrict__ y,
        const float* __restrict__ dww, const float* __restrict__ dwb,
        bf16* __restrict__ z) {
    __shared__ float wl[25 * 360];   // [tap][ch]
    __shared__ float bl[360];
    const int tid = threadIdx.x;
    for (int e = tid; e < 9000; e += 256) {
        const int ch = e / 25;
        const int tap = e - ch * 25;
        wl[tap * 360 + ch] = dww[e];
    }
    for (int e = tid; e < 360; e += 256) bl[e] = dwb[e];
    __syncthreads();

    const int gid = blockIdx.x * 256 + tid;
    const int g0  = gid / 180;
    const int pr  = gid - g0 * 180;
    const int xg  = g0 & 31;
    const int u   = g0 >> 5;
    const int im  = u >> 4;
    const int ph0 = (u & 15) << 3;         // band start row (8 rows per band)
    const int x0  = xg << 2;
    const float2 bias2 = *(const float2*)(bl + 2 * pr);

    const bf162* ybase = (const bf162*)y + ((long)im << 14) * 180 + pr;
    bf162*       zbase = (bf162*)z + (((long)im << 14) + ((long)ph0 << 7) + x0) * 180 + pr;

#define LOADROW(R, HY) { \
    const int hy_ = (HY); \
    if ((unsigned)hy_ < 128u) { \
        const bf162* row_ = ybase + ((long)hy_ << 7) * 180; \
        _Pragma("unroll") \
        for (int xx = 0; xx < 8; ++xx) { \
            const int wx_ = x0 + xx - 2; \
            R[xx] = ((unsigned)wx_ < 128u) ? __bfloat1622float2(row_[wx_ * 180]) \
                                           : make_float2(0.f, 0.f); \
        } \
    } else { \
        _Pragma("unroll") for (int xx = 0; xx < 8; ++xx) R[xx] = make_float2(0.f, 0.f); \
    } }

#define ACCJ(R, J) { \
    _Pragma("unroll") \
    for (int d = 0; d < 5; ++d) { \
        const float2 w2 = *(const float2*)(wl + ((J) * 5 + d) * 360 + 2 * pr); \
        s0.x += R[d].x     * w2.x; s0.y += R[d].y     * w2.y; \
        s1.x += R[d + 1].x * w2.x; s1.y += R[d + 1].y * w2.y; \
        s2.x += R[d + 2].x * w2.x; s2.y += R[d + 2].y * w2.y; \
        s3.x += R[d + 3].x * w2.x; s3.y += R[d + 3].y * w2.y; \
    } }

#define STEP(T, RA, RB, RC, RD, RE, RP, PF) { \
    if (PF) LOADROW(RP, ph0 + (T) + 3); \
    float2 s0 = bias2, s1 = bias2, s2 = bias2, s3 = bias2; \
    ACCJ(RA, 0); ACCJ(RB, 1); ACCJ(RC, 2); ACCJ(RD, 3); ACCJ(RE, 4); \
    bf162* zr = zbase + ((long)(T) << 7) * 180; \
    bf162 ov; \
    ov.x = __float2bfloat16(RC[2].x + gelu_f(s0.x)); \
    ov.y = __float2bfloat16(RC[2].y + gelu_f(s0.y)); zr[0]   = ov; \
    ov.x = __float2bfloat16(RC[3].x + gelu_f(s1.x)); \
    ov.y = __float2bfloat16(RC[3].y + gelu_f(s1.y)); zr[180] = ov; \
    ov.x = __float2bfloat16(RC[4].x + gelu_f(s2.x)); \
    ov.y = __float2bfloat16(RC[4].y + gelu_f(s2.y)); zr[360] = ov; \
    ov.x = __float2bfloat16(RC[5].x + gelu_f(s3.x)); \
    ov.y = __float2bfloat16(RC[5].y + gelu_f(s3.y)); zr[540] = ov; \
    }

    float2 r0[8], r1[8], r2[8], r3[8], r4[8], r5[8];
    LOADROW(r0, ph0 - 2);
    LOADROW(r1, ph0 - 1);
    LOADROW(r2, ph0);
    LOADROW(r3, ph0 + 1);
    LOADROW(r4, ph0 + 2);

    STEP(0, r0, r1, r2, r3, r4, r5, 1);
    STEP(1, r1, r2, r3, r4, r5, r0, 1);
    STEP(2, r2, r3, r4, r5, r0, r1, 1);
    STEP(3, r3, r4, r5, r0, r1, r2, 1);
    STEP(4, r4, r5, r0, r1, r2, r3, 1);
    STEP(5, r5, r0, r1, r2, r3, r4, 1);
    STEP(6, r0, r1, r2, r3, r4, r5, 1);
    STEP(7, r1, r2, r3, r4, r5, r0, 0);

#undef STEP
#undef ACCJ
#undef LOADROW
}

// ---------------- launch --------------------------------------------------------
extern "C" void kernel_launch(void* const* d_in, const int* in_sizes, int n_in,
                              void* d_out, int out_size, void* d_ws, size_t ws_size,
                              hipStream_t stream) {
    const float* x    = (const float*)d_in[0];
    // d_in[1] = attn_mask: unused (mask recomputed analytically in-kernel)
    const int*   rpi  = (const int*)d_in[2];
    const float* n1w  = (const float*)d_in[3];
    const float* n1b  = (const float*)d_in[4];
    const float* wqkv = (const float*)d_in[5];
    const float* bqkv = (const float*)d_in[6];
    const float* rpb  = (const float*)d_in[7];
    const float* pw   = (const float*)d_in[8];
    const float* pb   = (const float*)d_in[9];
    const float* n2w  = (const float*)d_in[10];
    const float* n2b  = (const float*)d_in[11];
    const float* f1w  = (const float*)d_in[12];
    const float* f1b  = (const float*)d_in[13];
    const float* dww  = (const float*)d_in[14];
    const float* dwb  = (const float*)d_in[15];
    const float* f2w  = (const float*)d_in[16];
    const float* f2b  = (const float*)d_in[17];
    float* out = (float*)d_out;

    // workspace: qkvb 141.6MB | abuf 47.2MB | guard | biasN 1.57MB | WT 0.59MB
    const size_t NEED = 540L * TOK * 2 + 180L * TOK * 2 + 192L * 2
                      + 393216L * 4 + 294912L * 2;
    if (ws_size < NEED) return;

    bf16* qkvb = (bf16*)d_ws;
    bf16* abuf = qkvb + 540L * TOK;
    bf16* ybuf = qkvb;                    // alias: qkv dead after attention
    bf16* zbuf = qkvb + 360L * TOK;       // spans qkvb tail + (abuf-adjacent)
    bf16* guard = qkvb + 720L * TOK;      // 192 zero shorts after abuf
    float* biasN = (float*)(guard + 192);
    bf16* wqkvT = (bf16*)(biasN + 393216);   // [576][192]
    bf16* projT = wqkvT + 110592;            // [192][192]
    bf16* fc1T  = projT + 36864;             // [384][192]
    bf16* fc2T  = fc1T + 73728;              // [192][384]

    wtrans_kernel<180, 540, 192, 576><<<432, 256, 0, stream>>>(wqkv, wqkvT);
    wtrans_kernel<180, 180, 192, 192><<<144, 256, 0, stream>>>(pw, projT);
    wtrans_kernel<180, 360, 192, 384><<<288, 256, 0, stream>>>(f1w, fc1T);
    wtrans_kernel<360, 180, 384, 192><<<288, 256, 0, stream>>>(f2w, fc2T);
    biast_kernel<<<256, 256, 0, stream>>>(rpb, rpi, biasN);
    guardz_kernel<<<1, 192, 0, stream>>>(guard);

    ln_kernel<<<32768, 256, 0, stream>>>(x, n1w, n1b, abuf);
    gemm_xstat<180, 1, 9, 540, 0><<<2048, 256, 0, stream>>>(abuf, wqkvT, bqkv, nullptr, qkvb);
    attn_mfma<<<3072, 256, 0, stream>>>(qkvb, biasN, abuf);         // abuf := attn_out
    gemm_xstat<180, 1, 3, 180, 2><<<2048, 256, 0, stream>>>(abuf, projT, pb, x, out);  // out := x2
    ln_kernel<<<32768, 256, 0, stream>>>(out, n2w, n2b, abuf);      // abuf := xn2
    gemm_xstat<180, 1, 6, 360, 1><<<2048, 256, 0, stream>>>(abuf, fc1T, f1b, nullptr, ybuf);
    dwconv_kernel<<<2880, 256, 0, stream>>>(ybuf, dww, dwb, zbuf);
    gemm_xstat<360, 2, 3, 180, 3><<<2048, 256, 0, stream>>>(zbuf, fc2T, f2b, out, out);
}